// Round 2
// baseline (287.291 us; speedup 1.0000x reference)
//
#include <hip/hip_runtime.h>
#include <hip/hip_bf16.h>

// ClasswiseECE: N=262144 rows, C=128 classes, 15 bins.
// zero ws -> [float4 loads, 2 rows/wave, register bin-0 accum, LDS rare bins,
//             block flush w/ skip-zero global atomics] -> 1-wave final reduce.

constexpr int N_BINS = 15;
constexpr int N_CLS  = 128;
constexpr int HIST   = N_CLS * N_BINS;  // 1920
constexpr int BLOCK  = 1024;            // 16 waves
constexpr int GRID   = 512;             // 2 blocks/CU -> 32 waves/CU

__global__ void zero_ws_kernel(int* __restrict__ ws, int n) {
    int i = blockIdx.x * blockDim.x + threadIdx.x;
    if (i < n) ws[i] = 0;
}

__global__ __launch_bounds__(BLOCK) void ece_hist_kernel(
        const float* __restrict__ logits, const int* __restrict__ labels,
        int N,
        int* __restrict__ g_counts, int* __restrict__ g_acc,
        float* __restrict__ g_conf, int* __restrict__ g_maxlab) {
    __shared__ int   s_counts[HIST];
    __shared__ int   s_acc[HIST];
    __shared__ float s_conf[HIST];
    for (int i = threadIdx.x; i < HIST; i += BLOCK) {
        s_counts[i] = 0; s_acc[i] = 0; s_conf[i] = 0.0f;
    }
    __syncthreads();

    const int lane = threadIdx.x & 63;
    const int wid  = threadIdx.x >> 6;
    const int half = lane >> 5;    // 0: row r, 1: row r+1
    const int q    = lane & 31;    // quad index -> classes 4q..4q+3
    const int wavesTotal = GRID * (BLOCK / 64);
    const int waveId = blockIdx.x * (BLOCK / 64) + wid;
    int rpw = (N + wavesTotal - 1) / wavesTotal;
    rpw += rpw & 1;                                  // even chunk
    const int row0 = min(waveId * rpw, N);
    const int row1 = min(row0 + rpw, N);

    // Per-lane register accumulators for bin 0 (99.6% of hits), classes 4q+j.
    int   cnt0[4] = {0, 0, 0, 0};
    int   acc0[4] = {0, 0, 0, 0};
    float conf0[4] = {0.0f, 0.0f, 0.0f, 0.0f};
    int labmax = 0;

    for (int row = row0; row + 1 < row1; row += 2) {
        const int myrow = row + half;
        const float4 v = *reinterpret_cast<const float4*>(
            logits + (size_t)myrow * N_CLS + q * 4);
        const int lab = labels[myrow];
        labmax = max(labmax, lab);

        // softmax over 128 elems held by a 32-lane half (4/lane)
        float m = fmaxf(fmaxf(v.x, v.y), fmaxf(v.z, v.w));
        #pragma unroll
        for (int s = 16; s; s >>= 1) m = fmaxf(m, __shfl_xor(m, s));
        float e[4];
        e[0] = __expf(v.x - m); e[1] = __expf(v.y - m);
        e[2] = __expf(v.z - m); e[3] = __expf(v.w - m);
        float t = (e[0] + e[1]) + (e[2] + e[3]);
        #pragma unroll
        for (int s = 16; s; s >>= 1) t += __shfl_xor(t, s);
        const float inv = 1.0f / t;

        #pragma unroll
        for (int j = 0; j < 4; ++j) {
            const float p = e[j] * inv;
            if (p > 0.0f) {                                   // p==0 -> no bin
                int b = min((int)ceilf(p * (float)N_BINS) - 1, N_BINS - 1);
                const int c = 4 * q + j;
                const int corr = (lab == c) ? 1 : 0;
                if (b == 0) {                                 // hot path: registers
                    cnt0[j] += 1; conf0[j] += p; acc0[j] += corr;
                } else {                                      // rare: LDS atomics
                    const int idx = c * N_BINS + b;
                    atomicAdd(&s_counts[idx], 1);
                    atomicAdd(&s_conf[idx], p);
                    if (corr) atomicAdd(&s_acc[idx], 1);
                }
            }
        }
    }
    // Tail (odd chunk) — unreachable for N=262144/8192 waves, kept for safety.
    if (((row1 - row0) & 1) && row1 > row0) {
        const int row = row1 - 1;
        if (half == 0) {
            const float4 v = *reinterpret_cast<const float4*>(
                logits + (size_t)row * N_CLS + q * 4);
            const int lab = labels[row];
            labmax = max(labmax, lab);
            float m = fmaxf(fmaxf(v.x, v.y), fmaxf(v.z, v.w));
            #pragma unroll
            for (int s = 16; s; s >>= 1) m = fmaxf(m, __shfl_xor(m, s));
            float e[4];
            e[0] = __expf(v.x - m); e[1] = __expf(v.y - m);
            e[2] = __expf(v.z - m); e[3] = __expf(v.w - m);
            float t = (e[0] + e[1]) + (e[2] + e[3]);
            #pragma unroll
            for (int s = 16; s; s >>= 1) t += __shfl_xor(t, s);
            const float inv = 1.0f / t;
            #pragma unroll
            for (int j = 0; j < 4; ++j) {
                const float p = e[j] * inv;
                if (p > 0.0f) {
                    int b = min((int)ceilf(p * (float)N_BINS) - 1, N_BINS - 1);
                    const int c = 4 * q + j;
                    const int corr = (lab == c) ? 1 : 0;
                    if (b == 0) { cnt0[j] += 1; conf0[j] += p; acc0[j] += corr; }
                    else {
                        const int idx = c * N_BINS + b;
                        atomicAdd(&s_counts[idx], 1);
                        atomicAdd(&s_conf[idx], p);
                        if (corr) atomicAdd(&s_acc[idx], 1);
                    }
                }
            }
        }
    }

    #pragma unroll
    for (int s = 32; s; s >>= 1) labmax = max(labmax, __shfl_xor(labmax, s));
    if (lane == 0) atomicMax(g_maxlab, labmax);

    // Merge register bin-0 accumulators into the block histogram.
    #pragma unroll
    for (int j = 0; j < 4; ++j) {
        const int idx = (4 * q + j) * N_BINS;     // bin 0 cell
        if (cnt0[j]) {
            atomicAdd(&s_counts[idx], cnt0[j]);
            atomicAdd(&s_conf[idx], conf0[j]);
        }
        if (acc0[j]) atomicAdd(&s_acc[idx], acc0[j]);
    }

    __syncthreads();
    // Flush block histogram to global; skip empty cells (higher bins sparse).
    for (int i = threadIdx.x; i < HIST; i += BLOCK) {
        const int c = s_counts[i];
        if (c) atomicAdd(&g_counts[i], c);
        const int a = s_acc[i];
        if (a) atomicAdd(&g_acc[i], a);
        const float f = s_conf[i];
        if (f != 0.0f) unsafeAtomicAdd(&g_conf[i], f);  // HW global_atomic_add_f32
    }
}

__global__ void ece_final_kernel(const int* __restrict__ g_counts,
                                 const int* __restrict__ g_acc,
                                 const float* __restrict__ g_conf,
                                 const int* __restrict__ g_maxlab,
                                 float* __restrict__ out, int N) {
    int lane = threadIdx.x;  // one wave
    int num_classes = *g_maxlab + 1;
    float total = 0.0f;
    #pragma unroll
    for (int j = 0; j < 2; ++j) {
        int c = lane + 64 * j;
        if (c < num_classes) {
            float pcs = 0.0f;
            for (int b = 0; b < N_BINS; ++b) {
                float cnt = (float)g_counts[c * N_BINS + b];
                if (cnt > 0.0f) {
                    float gap = fabsf(g_conf[c * N_BINS + b] / cnt
                                      - (float)g_acc[c * N_BINS + b] / cnt);
                    pcs += gap * cnt;
                }
            }
            total += pcs / (float)N;
        }
    }
    #pragma unroll
    for (int s = 32; s; s >>= 1) total += __shfl_xor(total, s);
    if (lane == 0) out[0] = total / (float)num_classes;
}

extern "C" void kernel_launch(void* const* d_in, const int* in_sizes, int n_in,
                              void* d_out, int out_size, void* d_ws, size_t ws_size,
                              hipStream_t stream) {
    const float* logits = (const float*)d_in[0];
    const int*   labels = (const int*)d_in[1];
    const int N = in_sizes[1];  // 262144 rows

    int*   ws       = (int*)d_ws;
    int*   g_counts = ws;                       // [HIST]
    int*   g_acc    = ws + HIST;                // [HIST]
    float* g_conf   = (float*)(ws + 2 * HIST);  // [HIST]
    int*   g_maxlab = ws + 3 * HIST;            // [1]

    const int nzero = 3 * HIST + 1;
    hipLaunchKernelGGL(zero_ws_kernel, dim3((nzero + 255) / 256), dim3(256), 0, stream,
                       ws, nzero);
    hipLaunchKernelGGL(ece_hist_kernel, dim3(GRID), dim3(BLOCK), 0, stream,
                       logits, labels, N, g_counts, g_acc, g_conf, g_maxlab);
    hipLaunchKernelGGL(ece_final_kernel, dim3(1), dim3(64), 0, stream,
                       g_counts, g_acc, g_conf, g_maxlab, (float*)d_out, N);
}

// Round 4
// 226.665 us; speedup vs baseline: 1.2675x; 1.2675x over previous
//
#include <hip/hip_runtime.h>
#include <hip/hip_bf16.h>

// ClasswiseECE, shuffle-free redesign:
//   - 4 lanes per row, 32 classes/lane in registers (8x dwordx4, deep MLP)
//   - softmax reductions: in-register trees + 2 quad_perm DPP ops (VALU only)
//   - bin0 (99.6% of elems) tracked algebraically via per-lane per-class psum regs
//   - rare bins (p*15>1 or p==0) via __any-gated LDS atomics
//   - accuracy: 1 LDS atomic per row (label cell)
//   - per-block LDS hist -> NSLOT-sliced global atomics -> tiny final kernel

constexpr int N_BINS  = 15;
constexpr int N_CLS   = 128;
constexpr int BSTRIDE = 16;                 // bins 0..14 + slot 15 = p==0 count
constexpr int HCELLS  = N_CLS * BSTRIDE;    // 2048
constexpr int NSLOT   = 4;                  // global hist slices (atomic contention /4)
constexpr int BLOCK   = 256;                // 4 waves; 64 rows per pass
constexpr int PASSES  = 4;                  // 256 rows per block
constexpr int ROWS_PER_BLOCK = 64 * PASSES;
constexpr int WS_WORDS = NSLOT * (3 * HCELLS + N_CLS) + 1;

template <int CTRL>
__device__ __forceinline__ float dpp_f32(float x) {
    return __int_as_float(__builtin_amdgcn_mov_dpp(__float_as_int(x), CTRL, 0xF, 0xF, true));
}
// quad butterfly (lanes 4q..4q+3): all 4 lanes get the reduction
__device__ __forceinline__ float quad_max(float x) {
    x = fmaxf(x, dpp_f32<0xB1>(x));   // quad_perm [1,0,3,2]  (xor 1)
    x = fmaxf(x, dpp_f32<0x4E>(x));   // quad_perm [2,3,0,1]  (xor 2)
    return x;
}
__device__ __forceinline__ float quad_sum(float x) {
    x += dpp_f32<0xB1>(x);
    x += dpp_f32<0x4E>(x);
    return x;
}

__global__ void zero_ws_kernel(int* __restrict__ ws, int n) {
    int i = blockIdx.x * blockDim.x + threadIdx.x;
    if (i < n) ws[i] = 0;
}

__global__ __launch_bounds__(BLOCK, 4) void ece_hist_kernel(
        const float* __restrict__ logits, const int* __restrict__ labels,
        int rows, int* __restrict__ ws) {
    __shared__ int   s_cnt[HCELLS];
    __shared__ float s_conf[HCELLS];
    __shared__ int   s_acc[HCELLS];
    __shared__ float s_ptot[N_CLS];
    __shared__ int   s_labmax;

    const int tid  = threadIdx.x;
    const int lane = tid & 63;
    const int q    = tid & 3;        // quarter-row: classes q*32 .. q*32+31
    const int quad = tid >> 2;       // 0..63: row within pass

    for (int i = tid; i < HCELLS; i += BLOCK) { s_cnt[i] = 0; s_conf[i] = 0.0f; s_acc[i] = 0; }
    for (int i = tid; i < N_CLS; i += BLOCK) s_ptot[i] = 0.0f;
    if (tid == 0) s_labmax = 0;
    __syncthreads();

    float psum[32];
    #pragma unroll
    for (int i = 0; i < 32; ++i) psum[i] = 0.0f;
    int labmax = 0;

    const int rowbase = blockIdx.x * ROWS_PER_BLOCK;

    #pragma unroll 1
    for (int pass = 0; pass < PASSES; ++pass) {
        const int row = rowbase + pass * 64 + quad;
        if (row < rows) {
            // ---- load 32 contiguous floats (this lane's quarter-row) ----
            float4 f4[8];
            const float4* vp = reinterpret_cast<const float4*>(
                logits + (size_t)row * N_CLS + q * 32);
            #pragma unroll
            for (int k = 0; k < 8; ++k) f4[k] = vp[k];
            float* v = reinterpret_cast<float*>(f4);

            const int lab  = labels[row];
            labmax = max(labmax, lab);
            const int labi = lab & 31;
            const bool qmatch = ((lab >> 5) == q);

            // ---- max: in-lane tree + quad DPP ----
            float w[16];
            #pragma unroll
            for (int i = 0; i < 16; ++i) w[i] = fmaxf(v[i], v[i + 16]);
            #pragma unroll
            for (int s = 8; s >= 1; s >>= 1)
                #pragma unroll
                for (int i = 0; i < 8; ++i) if (i < s) w[i] = fmaxf(w[i], w[i + s]);
            const float m = quad_max(w[0]);

            // ---- exp + sum ----
            #pragma unroll
            for (int i = 0; i < 32; ++i) v[i] = __expf(v[i] - m);
            float z[16];
            #pragma unroll
            for (int i = 0; i < 16; ++i) z[i] = v[i] + v[i + 16];
            #pragma unroll
            for (int s = 8; s >= 1; s >>= 1)
                #pragma unroll
                for (int i = 0; i < 8; ++i) if (i < s) z[i] = z[i] + z[i + s];
            const float inv = 1.0f / quad_sum(z[0]);

            // ---- binning: bin0 in registers, rare via __any-gated LDS ----
            float p_lab = 0.0f;
            #pragma unroll
            for (int i = 0; i < 32; ++i) {
                const float p = v[i] * inv;
                psum[i] += p;
                const float t15 = p * (float)N_BINS;
                const bool cond = (t15 > 1.0f) || (p == 0.0f);
                p_lab = (i == labi) ? p : p_lab;
                if (__any(cond)) {
                    if (cond) {
                        const int c = q * 32 + i;
                        if (p == 0.0f) {
                            atomicAdd(&s_cnt[c * BSTRIDE + 15], 1);  // zero-slot
                        } else {
                            const int b = min((int)ceilf(t15) - 1, N_BINS - 1);  // >=1 here
                            atomicAdd(&s_cnt[c * BSTRIDE + b], 1);
                            atomicAdd(&s_conf[c * BSTRIDE + b], p);
                        }
                    }
                }
            }
            // accuracy: one LDS atomic per row, from the label-owning lane
            if (qmatch && p_lab > 0.0f) {
                const float t15 = p_lab * (float)N_BINS;
                const int b = (t15 <= 1.0f) ? 0 : min((int)ceilf(t15) - 1, N_BINS - 1);
                atomicAdd(&s_acc[(lab & (N_CLS - 1)) * BSTRIDE + b], 1);
            }
        }
    }

    atomicMax(&s_labmax, labmax);

    // ---- psum flush: reduce the 4 same-class lanes per row16 (row_ror DPP),
    //      then 1-in-4 lanes do the LDS atomic ----
    #pragma unroll
    for (int i = 0; i < 32; ++i) {
        float x = psum[i];
        x += dpp_f32<0x124>(x);   // row_ror:4
        x += dpp_f32<0x128>(x);   // row_ror:8
        if ((lane & 12) == 0) atomicAdd(&s_ptot[q * 32 + i], x);
    }
    __syncthreads();

    // ---- block flush to sliced global hist (skip-zero) ----
    int* __restrict__ g_cnt  = ws;
    float* __restrict__ g_conf = (float*)(ws + NSLOT * HCELLS);
    int* __restrict__ g_acc  = ws + 2 * NSLOT * HCELLS;
    float* __restrict__ g_ptot = (float*)(ws + 3 * NSLOT * HCELLS);
    int* __restrict__ g_labmax = ws + 3 * NSLOT * HCELLS + NSLOT * N_CLS;
    const int slot = blockIdx.x & (NSLOT - 1);

    for (int i = tid; i < HCELLS; i += BLOCK) {
        const int cv = s_cnt[i];
        if (cv) atomicAdd(&g_cnt[slot * HCELLS + i], cv);
        const float cf = s_conf[i];
        if (cf != 0.0f) unsafeAtomicAdd(&g_conf[slot * HCELLS + i], cf);
        const int av = s_acc[i];
        if (av) atomicAdd(&g_acc[slot * HCELLS + i], av);
    }
    for (int i = tid; i < N_CLS; i += BLOCK) {
        const float pv = s_ptot[i];
        if (pv != 0.0f) unsafeAtomicAdd(&g_ptot[slot * N_CLS + i], pv);
    }
    if (tid == 0) atomicMax(g_labmax, s_labmax);
}

__global__ void ece_final_kernel(const int* __restrict__ ws, float* __restrict__ out, int rows) {
    __shared__ float s_pcs[N_CLS];
    const int c = threadIdx.x;  // 128 threads

    const int*   g_cnt  = ws;
    const float* g_conf = (const float*)(ws + NSLOT * HCELLS);
    const int*   g_acc  = ws + 2 * NSLOT * HCELLS;
    const float* g_ptot = (const float*)(ws + 3 * NSLOT * HCELLS);
    const int*   g_labmax = ws + 3 * NSLOT * HCELLS + NSLOT * N_CLS;

    float ptot = 0.0f;
    int   cntb[N_BINS];   // [0] unused
    float confb[N_BINS];
    int   accb[N_BINS];
    int   zeros = 0;
    #pragma unroll
    for (int b = 0; b < N_BINS; ++b) { cntb[b] = 0; confb[b] = 0.0f; accb[b] = 0; }

    for (int s = 0; s < NSLOT; ++s) {
        ptot += g_ptot[s * N_CLS + c];
        const int base = s * HCELLS + c * BSTRIDE;
        zeros += g_cnt[base + 15];
        accb[0] += g_acc[base + 0];
        #pragma unroll
        for (int b = 1; b < N_BINS; ++b) {
            cntb[b]  += g_cnt[base + b];
            confb[b] += g_conf[base + b];
            accb[b]  += g_acc[base + b];
        }
    }

    long cnt_rest = 0;
    float conf_rest = 0.0f;
    #pragma unroll
    for (int b = 1; b < N_BINS; ++b) { cnt_rest += cntb[b]; conf_rest += confb[b]; }
    const long cnt0 = (long)rows - cnt_rest - zeros;
    const float conf0 = ptot - conf_rest;

    float pcs = 0.0f;
    if (cnt0 > 0) pcs += fabsf(conf0 - (float)accb[0]);
    #pragma unroll
    for (int b = 1; b < N_BINS; ++b)
        if (cntb[b] > 0) pcs += fabsf(confb[b] - (float)accb[b]);
    s_pcs[c] = pcs / (float)rows;
    __syncthreads();

    if (c == 0) {
        const int nc = *g_labmax + 1;
        float tot = 0.0f;
        for (int j = 0; j < nc && j < N_CLS; ++j) tot += s_pcs[j];
        out[0] = tot / (float)nc;
    }
}

extern "C" void kernel_launch(void* const* d_in, const int* in_sizes, int n_in,
                              void* d_out, int out_size, void* d_ws, size_t ws_size,
                              hipStream_t stream) {
    const float* logits = (const float*)d_in[0];
    const int*   labels = (const int*)d_in[1];
    const int rows = in_sizes[1];  // 262144

    int* ws = (int*)d_ws;
    hipLaunchKernelGGL(zero_ws_kernel, dim3((WS_WORDS + 255) / 256), dim3(256), 0, stream,
                       ws, WS_WORDS);
    const int grid = (rows + ROWS_PER_BLOCK - 1) / ROWS_PER_BLOCK;  // 1024
    hipLaunchKernelGGL(ece_hist_kernel, dim3(grid), dim3(BLOCK), 0, stream,
                       logits, labels, rows, ws);
    hipLaunchKernelGGL(ece_final_kernel, dim3(1), dim3(N_CLS), 0, stream,
                       ws, (float*)d_out, rows);
}

// Round 7
// 224.152 us; speedup vs baseline: 1.2817x; 1.0112x over previous
//
#include <hip/hip_runtime.h>
#include <hip/hip_bf16.h>

// ClasswiseECE v3: 8 lanes/row, 16 classes/lane (low VGPR, no spill).
//   - softmax reduce across 8 adjacent lanes: 3 DPP ops (xor1, xor2, half_mirror)
//   - bin0 (~99.6% of elems) algebraic via per-lane psum[16] registers
//   - rare bins via __any-gated LDS atomics; accuracy: 1 LDS atomic/row
//   - per-block LDS hist -> NSLOT-sliced global atomics -> tiny final kernel

constexpr int N_BINS  = 15;
constexpr int N_CLS   = 128;
constexpr int BSTRIDE = 16;                 // bins 0..14 + slot 15 = p==0 count
constexpr int HCELLS  = N_CLS * BSTRIDE;    // 2048
constexpr int NSLOT   = 4;                  // global hist slices
constexpr int BLOCK   = 256;
constexpr int ROWS_PER_PASS  = BLOCK / 8;   // 32
constexpr int PASSES  = 8;
constexpr int ROWS_PER_BLOCK = ROWS_PER_PASS * PASSES;  // 256
constexpr int WS_WORDS = NSLOT * (3 * HCELLS + N_CLS) + 1;

template <int CTRL>
__device__ __forceinline__ float dpp_f32(float x) {
    return __int_as_float(__builtin_amdgcn_mov_dpp(__float_as_int(x), CTRL, 0xF, 0xF, true));
}
// reduce across the 8 adjacent lanes sharing a row (lanes 8r..8r+7)
__device__ __forceinline__ float dpp8_max(float x) {
    x = fmaxf(x, dpp_f32<0xB1>(x));    // quad_perm [1,0,3,2]  : xor 1
    x = fmaxf(x, dpp_f32<0x4E>(x));    // quad_perm [2,3,0,1]  : xor 2
    x = fmaxf(x, dpp_f32<0x141>(x));   // row_half_mirror      : other quad in 8-group
    return x;
}
__device__ __forceinline__ float dpp8_sum(float x) {
    x += dpp_f32<0xB1>(x);
    x += dpp_f32<0x4E>(x);
    x += dpp_f32<0x141>(x);
    return x;
}

__global__ void zero_ws_kernel(int* __restrict__ ws, int n) {
    int i = blockIdx.x * blockDim.x + threadIdx.x;
    if (i < n) ws[i] = 0;
}

__global__ __launch_bounds__(BLOCK) void ece_hist_kernel(
        const float* __restrict__ logits, const int* __restrict__ labels,
        int rows, int* __restrict__ ws) {
    __shared__ int   s_cnt[HCELLS];
    __shared__ float s_conf[HCELLS];
    __shared__ int   s_acc[HCELLS];
    __shared__ float s_ptot[N_CLS];
    __shared__ int   s_labmax;

    const int tid = threadIdx.x;
    const int o   = tid & 7;    // 16-class block: classes o*16 .. o*16+15
    const int r   = tid >> 3;   // row within pass (0..31)

    for (int i = tid; i < HCELLS; i += BLOCK) { s_cnt[i] = 0; s_conf[i] = 0.0f; s_acc[i] = 0; }
    for (int i = tid; i < N_CLS; i += BLOCK) s_ptot[i] = 0.0f;
    if (tid == 0) s_labmax = 0;
    __syncthreads();

    float psum[16];
    #pragma unroll
    for (int i = 0; i < 16; ++i) psum[i] = 0.0f;
    int labmax = 0;

    const int rowbase = blockIdx.x * ROWS_PER_BLOCK;

    #pragma unroll 1
    for (int pass = 0; pass < PASSES; ++pass) {
        const int row = rowbase + pass * ROWS_PER_PASS + r;
        if (row < rows) {
            const float4* vp = reinterpret_cast<const float4*>(
                logits + (size_t)row * N_CLS + o * 16);
            const float4 a = vp[0], b = vp[1], c4 = vp[2], d = vp[3];
            // scalar, constant-indexed (SROA-friendly; no aliasing casts)
            float v[16];
            v[0]=a.x;  v[1]=a.y;  v[2]=a.z;  v[3]=a.w;
            v[4]=b.x;  v[5]=b.y;  v[6]=b.z;  v[7]=b.w;
            v[8]=c4.x; v[9]=c4.y; v[10]=c4.z; v[11]=c4.w;
            v[12]=d.x; v[13]=d.y; v[14]=d.z; v[15]=d.w;

            const int lab = labels[row];
            labmax = max(labmax, lab);
            const int labo = lab >> 4;
            const int labi = lab & 15;

            // ---- max: in-lane tree (15 fmax) + 3 DPP ----
            float m8[8];
            #pragma unroll
            for (int i = 0; i < 8; ++i) m8[i] = fmaxf(v[i], v[i + 8]);
            float m4a = fmaxf(m8[0], m8[4]), m4b = fmaxf(m8[1], m8[5]);
            float m4c = fmaxf(m8[2], m8[6]), m4d = fmaxf(m8[3], m8[7]);
            float m = fmaxf(fmaxf(m4a, m4b), fmaxf(m4c, m4d));
            m = dpp8_max(m);

            // ---- exp + sum: 15 adds + 3 DPP ----
            #pragma unroll
            for (int i = 0; i < 16; ++i) v[i] = __expf(v[i] - m);
            float z8[8];
            #pragma unroll
            for (int i = 0; i < 8; ++i) z8[i] = v[i] + v[i + 8];
            float z4a = z8[0] + z8[4], z4b = z8[1] + z8[5];
            float z4c = z8[2] + z8[6], z4d = z8[3] + z8[7];
            float s = (z4a + z4b) + (z4c + z4d);
            const float inv = 1.0f / dpp8_sum(s);

            // ---- binning: bin0 in registers, rare bins via __any-gated LDS ----
            float p_lab = 0.0f;
            #pragma unroll
            for (int i = 0; i < 16; ++i) {
                const float p = v[i] * inv;
                psum[i] += p;
                const float t15 = p * (float)N_BINS;
                const bool cond = (t15 > 1.0f) || (p == 0.0f);
                p_lab = (i == labi) ? p : p_lab;
                if (__any(cond)) {
                    if (cond) {
                        const int c = o * 16 + i;
                        if (p == 0.0f) {
                            atomicAdd(&s_cnt[c * BSTRIDE + 15], 1);  // zero-slot
                        } else {
                            const int b = min((int)ceilf(t15) - 1, N_BINS - 1);
                            atomicAdd(&s_cnt[c * BSTRIDE + b], 1);
                            atomicAdd(&s_conf[c * BSTRIDE + b], p);
                        }
                    }
                }
            }
            // accuracy: one LDS atomic per row from the label-owning lane
            if (o == labo && p_lab > 0.0f) {
                const float t15 = p_lab * (float)N_BINS;
                const int b = (t15 <= 1.0f) ? 0 : min((int)ceilf(t15) - 1, N_BINS - 1);
                atomicAdd(&s_acc[lab * BSTRIDE + b], 1);
            }
        }
    }

    atomicMax(&s_labmax, labmax);
    // psum flush (once per kernel): 16 LDS atomics/thread
    #pragma unroll
    for (int i = 0; i < 16; ++i) atomicAdd(&s_ptot[o * 16 + i], psum[i]);
    __syncthreads();

    // ---- block flush to sliced global hist (skip-zero) ----
    int*   __restrict__ g_cnt    = ws;
    float* __restrict__ g_conf   = (float*)(ws + NSLOT * HCELLS);
    int*   __restrict__ g_acc    = ws + 2 * NSLOT * HCELLS;
    float* __restrict__ g_ptot   = (float*)(ws + 3 * NSLOT * HCELLS);
    int*   __restrict__ g_labmax = ws + 3 * NSLOT * HCELLS + NSLOT * N_CLS;
    const int slot = blockIdx.x & (NSLOT - 1);

    for (int i = tid; i < HCELLS; i += BLOCK) {
        const int cv = s_cnt[i];
        if (cv) atomicAdd(&g_cnt[slot * HCELLS + i], cv);
        const float cf = s_conf[i];
        if (cf != 0.0f) unsafeAtomicAdd(&g_conf[slot * HCELLS + i], cf);
        const int av = s_acc[i];
        if (av) atomicAdd(&g_acc[slot * HCELLS + i], av);
    }
    for (int i = tid; i < N_CLS; i += BLOCK) {
        const float pv = s_ptot[i];
        if (pv != 0.0f) unsafeAtomicAdd(&g_ptot[slot * N_CLS + i], pv);
    }
    if (tid == 0) atomicMax(g_labmax, s_labmax);
}

__global__ void ece_final_kernel(const int* __restrict__ ws, float* __restrict__ out, int rows) {
    __shared__ float s_pcs[N_CLS];
    const int c = threadIdx.x;  // 128 threads

    const int*   g_cnt    = ws;
    const float* g_conf   = (const float*)(ws + NSLOT * HCELLS);
    const int*   g_acc    = ws + 2 * NSLOT * HCELLS;
    const float* g_ptot   = (const float*)(ws + 3 * NSLOT * HCELLS);
    const int*   g_labmax = ws + 3 * NSLOT * HCELLS + NSLOT * N_CLS;

    float ptot = 0.0f;
    int   cntb[N_BINS];
    float confb[N_BINS];
    int   accb[N_BINS];
    int   zeros = 0;
    #pragma unroll
    for (int b = 0; b < N_BINS; ++b) { cntb[b] = 0; confb[b] = 0.0f; accb[b] = 0; }

    for (int s = 0; s < NSLOT; ++s) {
        ptot += g_ptot[s * N_CLS + c];
        const int base = s * HCELLS + c * BSTRIDE;
        zeros += g_cnt[base + 15];
        accb[0] += g_acc[base + 0];
        #pragma unroll
        for (int b = 1; b < N_BINS; ++b) {
            cntb[b]  += g_cnt[base + b];
            confb[b] += g_conf[base + b];
            accb[b]  += g_acc[base + b];
        }
    }

    long  cnt_rest = 0;
    float conf_rest = 0.0f;
    #pragma unroll
    for (int b = 1; b < N_BINS; ++b) { cnt_rest += cntb[b]; conf_rest += confb[b]; }
    const long  cnt0  = (long)rows - cnt_rest - zeros;
    const float conf0 = ptot - conf_rest;

    float pcs = 0.0f;
    if (cnt0 > 0) pcs += fabsf(conf0 - (float)accb[0]);
    #pragma unroll
    for (int b = 1; b < N_BINS; ++b)
        if (cntb[b] > 0) pcs += fabsf(confb[b] - (float)accb[b]);
    s_pcs[c] = pcs / (float)rows;
    __syncthreads();

    if (c == 0) {
        const int nc = *g_labmax + 1;
        float tot = 0.0f;
        for (int j = 0; j < nc && j < N_CLS; ++j) tot += s_pcs[j];
        out[0] = tot / (float)nc;
    }
}

extern "C" void kernel_launch(void* const* d_in, const int* in_sizes, int n_in,
                              void* d_out, int out_size, void* d_ws, size_t ws_size,
                              hipStream_t stream) {
    const float* logits = (const float*)d_in[0];
    const int*   labels = (const int*)d_in[1];
    const int rows = in_sizes[1];  // 262144

    int* ws = (int*)d_ws;
    hipLaunchKernelGGL(zero_ws_kernel, dim3((WS_WORDS + 255) / 256), dim3(256), 0, stream,
                       ws, WS_WORDS);
    const int grid = (rows + ROWS_PER_BLOCK - 1) / ROWS_PER_BLOCK;  // 1024
    hipLaunchKernelGGL(ece_hist_kernel, dim3(grid), dim3(BLOCK), 0, stream,
                       logits, labels, rows, ws);
    hipLaunchKernelGGL(ece_final_kernel, dim3(1), dim3(N_CLS), 0, stream,
                       ws, (float*)d_out, rows);
}